// Round 4
// baseline (236.961 us; speedup 1.0000x reference)
//
#include <hip/hip_runtime.h>
#include <stdint.h>
#include <stddef.h>

#define Bn 32
#define Cc 512
#define Hh 40
#define Ww 40
#define Npix 1600
#define NCx 20
#define NCELL (Bn*Npix)      // 51200
#define CONF 0.3f
#define NMS_T 0.5f
#define NOUT 25
#define WSTRIDE 32           // padded packed-weight row stride (floats), rows 128B-aligned

// k1 geometry: 128 cells/block (tail block per image: 64), 4 waves split C
#define CB 128
#define BPI 13               // 12*128 + 64 = 1600
#define NWAVE 4
#define CR (Cc/NWAVE)        // 128 channels per wave

// workspace layout (float offsets)
#define WS_WPK    0
#define WS_BOXES  (WS_WPK + (size_t)Cc*WSTRIDE)
#define WS_SCORES (WS_BOXES + (size_t)NCELL*4)
#define WS_LABELS (WS_SCORES + (size_t)NCELL)

__device__ __forceinline__ float sigmoidf_(float x) {
    return 1.0f / (1.0f + expf(-x));
}

// ---------------- Kernel 0: pack weights into [c][WSTRIDE] rows ----------------
__global__ __launch_bounds__(64) void k0_pack(
    const float* __restrict__ w_obj, const float* __restrict__ w_cls,
    const float* __restrict__ w_reg, float* __restrict__ Wpk)
{
    int c = blockIdx.x * 64 + threadIdx.x;
    if (c < Cc) {
        float* row = Wpk + (size_t)c * WSTRIDE;
        row[0] = w_obj[c];
        #pragma unroll
        for (int o = 0; o < NCx; ++o) row[1 + o] = w_cls[o * Cc + c];
        #pragma unroll
        for (int o = 0; o < 4; ++o)   row[21 + o] = w_reg[o * Cc + c];
        row[25] = 0.f; row[26] = 0.f; row[27] = 0.f;   // pad (read by float4 below)
        row[28] = 0.f; row[29] = 0.f; row[30] = 0.f; row[31] = 0.f;
    }
}

// ---------------- Kernel 1: fused GEMM + reduce + decode + out-init ----------------
// block = 256 thr (4 waves). Wave w handles channels [w*128, w*128+128) for the
// block's 128 cells (float2 per lane). Weights read as explicit float4 vectors
// (guaranteed dwordx4, L2-resident 57KB working set). LDS reduce across waves
// (SEQUENTIAL order — bit-identical to the R0/R3 proven arithmetic).
__global__ __launch_bounds__(256) void k1_fused(
    const float* __restrict__ feat, const float* __restrict__ Wpk,
    const float* __restrict__ b_obj, const float* __restrict__ b_cls,
    const float* __restrict__ b_reg,
    float* __restrict__ out, float* __restrict__ ws_boxes,
    float* __restrict__ ws_scores, int* __restrict__ ws_labels)
{
    __shared__ float red[NOUT][CB][5];   // [o][cell][wave], stride 5

    const int tid = threadIdx.x;
    const int w   = __builtin_amdgcn_readfirstlane(tid >> 6);
    const int l   = tid & 63;
    const int b   = blockIdx.x / BPI;
    const int j   = blockIdx.x % BPI;
    const int n0  = j * CB;
    const int nc  = (j == BPI - 1) ? (Npix - n0) : CB;         // 128 or 64 (tail)

    float2 acc[NOUT];
    #pragma unroll
    for (int o = 0; o < NOUT; ++o) acc[o] = make_float2(0.f, 0.f);

    const int cw0 = w * CR;
    const bool active = (2 * l < nc);
    if (active) {
        const float* fp  = feat + (size_t)b * (Cc * Npix) + (size_t)cw0 * Npix + (n0 + 2 * l);
        const float* wr0 = Wpk + (size_t)cw0 * WSTRIDE;
        #pragma unroll 2
        for (int cc = 0; cc < CR; ++cc) {
            float2 x = *(const float2*)(fp + (size_t)cc * Npix);
            const float4* wq = (const float4*)(wr0 + cc * WSTRIDE);
            #pragma unroll
            for (int q = 0; q < 6; ++q) {
                float4 wv = wq[q];
                const int ob = q * 4;
                acc[ob+0].x = fmaf(x.x, wv.x, acc[ob+0].x);
                acc[ob+0].y = fmaf(x.y, wv.x, acc[ob+0].y);
                acc[ob+1].x = fmaf(x.x, wv.y, acc[ob+1].x);
                acc[ob+1].y = fmaf(x.y, wv.y, acc[ob+1].y);
                acc[ob+2].x = fmaf(x.x, wv.z, acc[ob+2].x);
                acc[ob+2].y = fmaf(x.y, wv.z, acc[ob+2].y);
                acc[ob+3].x = fmaf(x.x, wv.w, acc[ob+3].x);
                acc[ob+3].y = fmaf(x.y, wv.w, acc[ob+3].y);
            }
            float4 wv6 = wq[6];                                  // only .x is real (o=24)
            acc[24].x = fmaf(x.x, wv6.x, acc[24].x);
            acc[24].y = fmaf(x.y, wv6.x, acc[24].y);
        }
        #pragma unroll
        for (int o = 0; o < NOUT; ++o) {
            red[o][2 * l][w]     = acc[o].x;
            red[o][2 * l + 1][w] = acc[o].y;
        }
    }
    __syncthreads();

    if (tid < nc) {
        float v[NOUT];
        // SEQUENTIAL combine (((w0+w1)+w2)+w3) — proven ordering.
        #pragma unroll
        for (int o = 0; o < NOUT; ++o) v[o] = red[o][tid][0];
        #pragma unroll
        for (int ch = 1; ch < NWAVE; ++ch) {
            #pragma unroll
            for (int o = 0; o < NOUT; ++o) v[o] += red[o][tid][ch];
        }

        float obj = v[0] + b_obj[0];
        float m = -1e30f; int label = 0;
        #pragma unroll
        for (int o = 0; o < NCx; ++o) {
            float cv = v[1 + o] + b_cls[o];
            if (cv > m) { m = cv; label = o; }   // strict > == first-max (argmax)
        }
        float r0 = v[21] + b_reg[0], r1 = v[22] + b_reg[1];
        float r2 = v[23] + b_reg[2], r3 = v[24] + b_reg[3];

        int n = n0 + tid;
        int g = b * Npix + n;
        int gy = n / Ww, gx = n % Ww;
        float cx = (sigmoidf_(r0) + (float)gx) * 32.0f;
        float cy = (sigmoidf_(r1) + (float)gy) * 32.0f;
        float bw = expf(r2) * 32.0f;
        float bh = expf(r3) * 32.0f;
        float x1 = cx - bw * 0.5f, y1 = cy - bh * 0.5f;
        float x2 = cx + bw * 0.5f, y2 = cy + bh * 0.5f;
        float score = sqrtf(sigmoidf_(obj) * sigmoidf_(m));

        ((float4*)ws_boxes)[g] = make_float4(x1, y1, x2, y2);
        ws_scores[g] = score;
        ws_labels[g] = label;

        float* orow = out + (size_t)g * 5;
        orow[0] = 0.f; orow[1] = 0.f; orow[2] = 0.f; orow[3] = 0.f; orow[4] = 0.f;
        out[(size_t)NCELL * 5 + g] = (float)label;
        out[(size_t)NCELL * 6 + g] = 0.f;
    }
}

// ---------------- Kernel 3: per-(image,class) greedy NMS (proven, unchanged) ----------------
#define KSUP 320
#define WUMAX ((KSUP + 31) / 32)   // 10

__global__ __launch_bounds__(256) void k3_nms(
    const float4* __restrict__ ws_boxes, const float* __restrict__ ws_scores,
    const int* __restrict__ ws_labels, float* __restrict__ out)
{
    __shared__ unsigned int cnt;
    __shared__ unsigned long long keys[2048];
    __shared__ float bx1[Npix], by1[Npix], bx2[Npix], by2[Npix], bar[Npix];
    __shared__ unsigned int sup[KSUP * WUMAX];   // reused as keep-flags later
    __shared__ unsigned int keepbits[WUMAX];

    const int tid = threadIdx.x;
    const int b   = blockIdx.x / NCx;
    const int cls = blockIdx.x % NCx;
    const int gbase = b * Npix;

    if (tid == 0) cnt = 0;
    __syncthreads();

    for (int n = tid; n < Npix; n += 256) {
        float s = ws_scores[gbase + n];
        if (s > CONF && ws_labels[gbase + n] == cls) {
            unsigned int pos = atomicAdd(&cnt, 1u);
            unsigned int sb = __float_as_uint(s);
            keys[pos] = ((unsigned long long)(~sb) << 32) | (unsigned int)n;
        }
    }
    __syncthreads();
    const int k = (int)cnt;
    if (k == 0) return;

    int M = 2; while (M < k) M <<= 1;
    for (int s = tid; s < M; s += 256) if (s >= k) keys[s] = ~0ull;
    __syncthreads();

    for (int sz = 2; sz <= M; sz <<= 1) {
        for (int st = sz >> 1; st > 0; st >>= 1) {
            for (int t = tid; t < M; t += 256) {
                int p = t ^ st;
                if (p > t) {
                    unsigned long long a = keys[t], c = keys[p];
                    bool up = ((t & sz) == 0);
                    if (up ? (a > c) : (a < c)) { keys[t] = c; keys[p] = a; }
                }
            }
            __syncthreads();
        }
    }

    for (int s = tid; s < k; s += 256) {
        int n = (int)(unsigned int)keys[s];
        float4 bx = ws_boxes[gbase + n];
        bx1[s] = bx.x; by1[s] = bx.y; bx2[s] = bx.z; by2[s] = bx.w;
        bar[s] = (bx.z - bx.x) * (bx.w - bx.y);
    }
    __syncthreads();

    if (k <= KSUP) {
        const int wu = (k + 31) >> 5;
        for (int t = tid; t < k * wu; t += 256) {
            int i = t / wu, w = t - (t / wu) * wu;
            unsigned int bits = 0;
            int j0 = w << 5;
            float xi1 = bx1[i], yi1 = by1[i], xi2 = bx2[i], yi2 = by2[i], ai = bar[i];
            for (int jj = 0; jj < 32; ++jj) {
                int j = j0 + jj;
                if (j > i && j < k) {
                    float xx1 = fmaxf(xi1, bx1[j]);
                    float yy1 = fmaxf(yi1, by1[j]);
                    float xx2 = fminf(xi2, bx2[j]);
                    float yy2 = fminf(yi2, by2[j]);
                    float inter = fmaxf(xx2 - xx1, 0.f) * fmaxf(yy2 - yy1, 0.f);
                    float uni = ai + bar[j] - inter;
                    if (inter / uni > NMS_T) bits |= (1u << jj);
                }
            }
            sup[i * wu + w] = bits;
        }
        if (tid < wu) {
            int rem = k - (tid << 5);
            keepbits[tid] = (rem >= 32) ? 0xFFFFFFFFu : ((1u << rem) - 1u);
        }
        __syncthreads();

        if (tid < 64) {
            for (int i = 0; i < k; ++i) {
                unsigned int cur = keepbits[i >> 5];
                if ((cur >> (i & 31)) & 1u) {
                    if (tid < wu) keepbits[tid] &= ~sup[i * wu + tid];
                }
            }
            unsigned int* keepF = sup;
            for (int s2 = tid; s2 < k; s2 += 64)
                keepF[s2] = (keepbits[s2 >> 5] >> (s2 & 31)) & 1u;
        }
        __syncthreads();
    } else {
        unsigned int* keepF = sup;
        for (int s = tid; s < k; s += 256) keepF[s] = 1u;
        __syncthreads();
        for (int i = 0; i < k; ++i) {
            __syncthreads();
            if (keepF[i]) {
                float xi1 = bx1[i], yi1 = by1[i], xi2 = bx2[i], yi2 = by2[i], ai = bar[i];
                for (int j = i + 1 + tid; j < k; j += 256) {
                    float xx1 = fmaxf(xi1, bx1[j]);
                    float yy1 = fmaxf(yi1, by1[j]);
                    float xx2 = fminf(xi2, bx2[j]);
                    float yy2 = fminf(yi2, by2[j]);
                    float inter = fmaxf(xx2 - xx1, 0.f) * fmaxf(yy2 - yy1, 0.f);
                    float uni = ai + bar[j] - inter;
                    if (inter / uni > NMS_T) keepF[j] = 0u;
                }
            }
        }
        __syncthreads();
    }

    unsigned int* keepF = sup;
    for (int s = tid; s < k; s += 256) {
        if (keepF[s]) {
            int n = (int)(unsigned int)keys[s];
            unsigned int sb = ~(unsigned int)(keys[s] >> 32);
            float sc = __uint_as_float(sb);
            float* orow = out + (size_t)(gbase + n) * 5;
            orow[0] = bx1[s]; orow[1] = by1[s];
            orow[2] = bx2[s]; orow[3] = by2[s];
            orow[4] = sc;
            out[(size_t)NCELL * 6 + gbase + n] = 1.0f;
        }
    }
}

extern "C" void kernel_launch(void* const* d_in, const int* in_sizes, int n_in,
                              void* d_out, int out_size, void* d_ws, size_t ws_size,
                              hipStream_t stream) {
    const float* feat  = (const float*)d_in[0];
    const float* w_obj = (const float*)d_in[1];
    const float* b_obj = (const float*)d_in[2];
    const float* w_cls = (const float*)d_in[3];
    const float* b_cls = (const float*)d_in[4];
    const float* w_reg = (const float*)d_in[5];
    const float* b_reg = (const float*)d_in[6];
    float* out = (float*)d_out;
    float* ws  = (float*)d_ws;

    float* Wpk    = ws + WS_WPK;
    float* boxes  = ws + WS_BOXES;
    float* scores = ws + WS_SCORES;
    int*   labels = (int*)(ws + WS_LABELS);

    k0_pack<<<(Cc + 63) / 64, 64, 0, stream>>>(w_obj, w_cls, w_reg, Wpk);
    k1_fused<<<Bn * BPI, 256, 0, stream>>>(feat, Wpk, b_obj, b_cls, b_reg,
                                           out, boxes, scores, labels);
    k3_nms<<<Bn * NCx, 256, 0, stream>>>((const float4*)boxes, scores, labels, out);
}

// Round 5
// 220.727 us; speedup vs baseline: 1.0735x; 1.0735x over previous
//
#include <hip/hip_runtime.h>
#include <stdint.h>
#include <stddef.h>

#define Bn 32
#define Cc 512
#define Hh 40
#define Ww 40
#define Npix 1600
#define NCx 20
#define NCELL (Bn*Npix)      // 51200
#define CONF 0.3f
#define NMS_T 0.5f
#define NOUT 25
#define WSTRIDE 32           // padded packed-weight row stride (floats), rows 128B-aligned

// k1 geometry: 64 cells/block (1 cell/lane), 4 waves split C, 25 tiles/image (no tail)
#define CB 64
#define BPI 25               // 25*64 = 1600
#define NWAVE 4
#define CR (Cc/NWAVE)        // 128 channels per wave

// workspace layout (float offsets)
#define WS_WPK    0
#define WS_BOXES  (WS_WPK + (size_t)Cc*WSTRIDE)
#define WS_SCORES (WS_BOXES + (size_t)NCELL*4)
#define WS_LABELS (WS_SCORES + (size_t)NCELL)

__device__ __forceinline__ float sigmoidf_(float x) {
    return 1.0f / (1.0f + expf(-x));
}

// ---------------- Kernel 0: pack weights into [c][WSTRIDE] rows ----------------
__global__ __launch_bounds__(64) void k0_pack(
    const float* __restrict__ w_obj, const float* __restrict__ w_cls,
    const float* __restrict__ w_reg, float* __restrict__ Wpk)
{
    int c = blockIdx.x * 64 + threadIdx.x;
    if (c < Cc) {
        float* row = Wpk + (size_t)c * WSTRIDE;
        row[0] = w_obj[c];
        #pragma unroll
        for (int o = 0; o < NCx; ++o) row[1 + o] = w_cls[o * Cc + c];
        #pragma unroll
        for (int o = 0; o < 4; ++o)   row[21 + o] = w_reg[o * Cc + c];
        row[25] = 0.f; row[26] = 0.f; row[27] = 0.f;
        row[28] = 0.f; row[29] = 0.f; row[30] = 0.f; row[31] = 0.f;
    }
}

// ---------------- Kernel 1: fused GEMM + reduce + decode + out-init ----------------
// block = 256 thr (4 waves). Wave w handles channels [w*128, w*128+128) for the
// block's 64 cells, ONE cell per lane (dword loads, 256B/wave, coalesced).
// LDS reduce 32KB -> 5 blocks/CU; grid 800 -> ~3.1 waves/SIMD for latency hiding.
// Per-accumulator FMA chains and sequential 4-chunk combine are bit-identical
// to the proven R0/R3 arithmetic.
__global__ __launch_bounds__(256) void k1_fused(
    const float* __restrict__ feat, const float* __restrict__ Wpk,
    const float* __restrict__ b_obj, const float* __restrict__ b_cls,
    const float* __restrict__ b_reg,
    float* __restrict__ out, float* __restrict__ ws_boxes,
    float* __restrict__ ws_scores, int* __restrict__ ws_labels)
{
    __shared__ float red[NOUT][CB][5];   // [o][cell][wave] = 32000 B

    const int tid = threadIdx.x;
    const int w   = __builtin_amdgcn_readfirstlane(tid >> 6);  // uniform -> scalar path
    const int l   = tid & 63;
    const int b   = blockIdx.x / BPI;
    const int j   = blockIdx.x % BPI;
    const int n0  = j * CB;

    float acc[NOUT];
    #pragma unroll
    for (int o = 0; o < NOUT; ++o) acc[o] = 0.f;

    const int cw0 = w * CR;
    {
        const float* fp  = feat + (size_t)b * (Cc * Npix) + (size_t)cw0 * Npix + (n0 + l);
        const float* wr0 = Wpk + (size_t)cw0 * WSTRIDE;
        #pragma unroll 4
        for (int cc = 0; cc < CR; ++cc) {
            float x = fp[(size_t)cc * Npix];
            const float4* wq = (const float4*)(wr0 + cc * WSTRIDE);  // uniform -> s_load
            #pragma unroll
            for (int q = 0; q < 6; ++q) {
                float4 wv = wq[q];
                const int ob = q * 4;
                acc[ob+0] = fmaf(x, wv.x, acc[ob+0]);
                acc[ob+1] = fmaf(x, wv.y, acc[ob+1]);
                acc[ob+2] = fmaf(x, wv.z, acc[ob+2]);
                acc[ob+3] = fmaf(x, wv.w, acc[ob+3]);
            }
            float4 wv6 = wq[6];                    // only .x is real (o=24)
            acc[24] = fmaf(x, wv6.x, acc[24]);
        }
        #pragma unroll
        for (int o = 0; o < NOUT; ++o) red[o][l][w] = acc[o];
    }
    __syncthreads();

    if (tid < CB) {
        float v[NOUT];
        // SEQUENTIAL combine (((w0+w1)+w2)+w3) — proven ordering.
        #pragma unroll
        for (int o = 0; o < NOUT; ++o) v[o] = red[o][tid][0];
        #pragma unroll
        for (int ch = 1; ch < NWAVE; ++ch) {
            #pragma unroll
            for (int o = 0; o < NOUT; ++o) v[o] += red[o][tid][ch];
        }

        float obj = v[0] + b_obj[0];
        float m = -1e30f; int label = 0;
        #pragma unroll
        for (int o = 0; o < NCx; ++o) {
            float cv = v[1 + o] + b_cls[o];
            if (cv > m) { m = cv; label = o; }   // strict > == first-max (argmax)
        }
        float r0 = v[21] + b_reg[0], r1 = v[22] + b_reg[1];
        float r2 = v[23] + b_reg[2], r3 = v[24] + b_reg[3];

        int n = n0 + tid;
        int g = b * Npix + n;
        int gy = n / Ww, gx = n % Ww;
        float cx = (sigmoidf_(r0) + (float)gx) * 32.0f;
        float cy = (sigmoidf_(r1) + (float)gy) * 32.0f;
        float bw = expf(r2) * 32.0f;
        float bh = expf(r3) * 32.0f;
        float x1 = cx - bw * 0.5f, y1 = cy - bh * 0.5f;
        float x2 = cx + bw * 0.5f, y2 = cy + bh * 0.5f;
        float score = sqrtf(sigmoidf_(obj) * sigmoidf_(m));

        ((float4*)ws_boxes)[g] = make_float4(x1, y1, x2, y2);
        ws_scores[g] = score;
        ws_labels[g] = label;

        float* orow = out + (size_t)g * 5;
        orow[0] = 0.f; orow[1] = 0.f; orow[2] = 0.f; orow[3] = 0.f; orow[4] = 0.f;
        out[(size_t)NCELL * 5 + g] = (float)label;
        out[(size_t)NCELL * 6 + g] = 0.f;
    }
}

// ---------------- Kernel 3: per-(image,class) greedy NMS (proven, unchanged) ----------------
#define KSUP 320
#define WUMAX ((KSUP + 31) / 32)   // 10

__global__ __launch_bounds__(256) void k3_nms(
    const float4* __restrict__ ws_boxes, const float* __restrict__ ws_scores,
    const int* __restrict__ ws_labels, float* __restrict__ out)
{
    __shared__ unsigned int cnt;
    __shared__ unsigned long long keys[2048];
    __shared__ float bx1[Npix], by1[Npix], bx2[Npix], by2[Npix], bar[Npix];
    __shared__ unsigned int sup[KSUP * WUMAX];   // reused as keep-flags later
    __shared__ unsigned int keepbits[WUMAX];

    const int tid = threadIdx.x;
    const int b   = blockIdx.x / NCx;
    const int cls = blockIdx.x % NCx;
    const int gbase = b * Npix;

    if (tid == 0) cnt = 0;
    __syncthreads();

    for (int n = tid; n < Npix; n += 256) {
        float s = ws_scores[gbase + n];
        if (s > CONF && ws_labels[gbase + n] == cls) {
            unsigned int pos = atomicAdd(&cnt, 1u);
            unsigned int sb = __float_as_uint(s);
            keys[pos] = ((unsigned long long)(~sb) << 32) | (unsigned int)n;
        }
    }
    __syncthreads();
    const int k = (int)cnt;
    if (k == 0) return;

    int M = 2; while (M < k) M <<= 1;
    for (int s = tid; s < M; s += 256) if (s >= k) keys[s] = ~0ull;
    __syncthreads();

    for (int sz = 2; sz <= M; sz <<= 1) {
        for (int st = sz >> 1; st > 0; st >>= 1) {
            for (int t = tid; t < M; t += 256) {
                int p = t ^ st;
                if (p > t) {
                    unsigned long long a = keys[t], c = keys[p];
                    bool up = ((t & sz) == 0);
                    if (up ? (a > c) : (a < c)) { keys[t] = c; keys[p] = a; }
                }
            }
            __syncthreads();
        }
    }

    for (int s = tid; s < k; s += 256) {
        int n = (int)(unsigned int)keys[s];
        float4 bx = ws_boxes[gbase + n];
        bx1[s] = bx.x; by1[s] = bx.y; bx2[s] = bx.z; by2[s] = bx.w;
        bar[s] = (bx.z - bx.x) * (bx.w - bx.y);
    }
    __syncthreads();

    if (k <= KSUP) {
        const int wu = (k + 31) >> 5;
        for (int t = tid; t < k * wu; t += 256) {
            int i = t / wu, w = t - (t / wu) * wu;
            unsigned int bits = 0;
            int j0 = w << 5;
            float xi1 = bx1[i], yi1 = by1[i], xi2 = bx2[i], yi2 = by2[i], ai = bar[i];
            for (int jj = 0; jj < 32; ++jj) {
                int j = j0 + jj;
                if (j > i && j < k) {
                    float xx1 = fmaxf(xi1, bx1[j]);
                    float yy1 = fmaxf(yi1, by1[j]);
                    float xx2 = fminf(xi2, bx2[j]);
                    float yy2 = fminf(yi2, by2[j]);
                    float inter = fmaxf(xx2 - xx1, 0.f) * fmaxf(yy2 - yy1, 0.f);
                    float uni = ai + bar[j] - inter;
                    if (inter / uni > NMS_T) bits |= (1u << jj);
                }
            }
            sup[i * wu + w] = bits;
        }
        if (tid < wu) {
            int rem = k - (tid << 5);
            keepbits[tid] = (rem >= 32) ? 0xFFFFFFFFu : ((1u << rem) - 1u);
        }
        __syncthreads();

        if (tid < 64) {
            for (int i = 0; i < k; ++i) {
                unsigned int cur = keepbits[i >> 5];
                if ((cur >> (i & 31)) & 1u) {
                    if (tid < wu) keepbits[tid] &= ~sup[i * wu + tid];
                }
            }
            unsigned int* keepF = sup;
            for (int s2 = tid; s2 < k; s2 += 64)
                keepF[s2] = (keepbits[s2 >> 5] >> (s2 & 31)) & 1u;
        }
        __syncthreads();
    } else {
        unsigned int* keepF = sup;
        for (int s = tid; s < k; s += 256) keepF[s] = 1u;
        __syncthreads();
        for (int i = 0; i < k; ++i) {
            __syncthreads();
            if (keepF[i]) {
                float xi1 = bx1[i], yi1 = by1[i], xi2 = bx2[i], yi2 = by2[i], ai = bar[i];
                for (int j = i + 1 + tid; j < k; j += 256) {
                    float xx1 = fmaxf(xi1, bx1[j]);
                    float yy1 = fmaxf(yi1, by1[j]);
                    float xx2 = fminf(xi2, bx2[j]);
                    float yy2 = fminf(yi2, by2[j]);
                    float inter = fmaxf(xx2 - xx1, 0.f) * fmaxf(yy2 - yy1, 0.f);
                    float uni = ai + bar[j] - inter;
                    if (inter / uni > NMS_T) keepF[j] = 0u;
                }
            }
        }
        __syncthreads();
    }

    unsigned int* keepF = sup;
    for (int s = tid; s < k; s += 256) {
        if (keepF[s]) {
            int n = (int)(unsigned int)keys[s];
            unsigned int sb = ~(unsigned int)(keys[s] >> 32);
            float sc = __uint_as_float(sb);
            float* orow = out + (size_t)(gbase + n) * 5;
            orow[0] = bx1[s]; orow[1] = by1[s];
            orow[2] = bx2[s]; orow[3] = by2[s];
            orow[4] = sc;
            out[(size_t)NCELL * 6 + gbase + n] = 1.0f;
        }
    }
}

extern "C" void kernel_launch(void* const* d_in, const int* in_sizes, int n_in,
                              void* d_out, int out_size, void* d_ws, size_t ws_size,
                              hipStream_t stream) {
    const float* feat  = (const float*)d_in[0];
    const float* w_obj = (const float*)d_in[1];
    const float* b_obj = (const float*)d_in[2];
    const float* w_cls = (const float*)d_in[3];
    const float* b_cls = (const float*)d_in[4];
    const float* w_reg = (const float*)d_in[5];
    const float* b_reg = (const float*)d_in[6];
    float* out = (float*)d_out;
    float* ws  = (float*)d_ws;

    float* Wpk    = ws + WS_WPK;
    float* boxes  = ws + WS_BOXES;
    float* scores = ws + WS_SCORES;
    int*   labels = (int*)(ws + WS_LABELS);

    k0_pack<<<(Cc + 63) / 64, 64, 0, stream>>>(w_obj, w_cls, w_reg, Wpk);
    k1_fused<<<Bn * BPI, 256, 0, stream>>>(feat, Wpk, b_obj, b_cls, b_reg,
                                           out, boxes, scores, labels);
    k3_nms<<<Bn * NCx, 256, 0, stream>>>((const float4*)boxes, scores, labels, out);
}